// Round 1
// baseline (140.197 us; speedup 1.0000x reference)
//
#include <hip/hip_runtime.h>

typedef _Float16 half8 __attribute__((ext_vector_type(8)));
typedef _Float16 half4v __attribute__((ext_vector_type(4)));
typedef float f32x4 __attribute__((ext_vector_type(4)));

// Problem sizes (fixed)
//   B=8, S=512, D=1024, H=16, HD=64; M = B*S = 4096
// ws layout (bytes):
#define OFF_SIN   0u
#define OFF_COS   (512u*32u*4u)                  // 64 KB each table
#define OFF_XH    (1u<<20)                       // 1MB: xh fp16 4096x1024 (8MB); reused for attn out
#define OFF_WQKVT (OFF_XH + 8u*1024u*1024u)      // 9MB: Wqkv^T fp16 3072x1024 (6MB)
#define OFF_WOT   (OFF_WQKVT + 6u*1024u*1024u)   // 15MB: Wo^T fp16 1024x1024 (2MB)
#define OFF_QKV   (OFF_WOT + 2u*1024u*1024u)     // 17MB: qkv fp16 4096x3072 (24MB) -> 41MB total
#define OFF_ATTN  OFF_XH

__device__ __forceinline__ void gload16(const _Float16* g, _Float16* l) {
  __builtin_amdgcn_global_load_lds((const __attribute__((address_space(1))) void*)g,
                                   (__attribute__((address_space(3))) void*)l, 16, 0, 0);
}

// ---- RoPE sin/cos table: 512 positions x 32 freqs (table duplicated across halves) ----
__global__ void rope_table_k(float* __restrict__ sin_t, float* __restrict__ cos_t) {
  int idx = blockIdx.x * 256 + threadIdx.x;
  if (idx >= 512 * 32) return;
  int pos = idx >> 5, j = idx & 31;
  float inv = powf(10000.0f, -(float)j * (1.0f / 32.0f));
  float f = (float)pos * inv;
  sin_t[idx] = sinf(f);
  cos_t[idx] = cosf(f);
}

// ---- fp32 -> fp16 convert (vectorized float4 -> half4) ----
__global__ void convert_f16_k(const float* __restrict__ in, _Float16* __restrict__ out, int n4) {
  int i = blockIdx.x * 256 + threadIdx.x;
  if (i >= n4) return;
  float4 v = ((const float4*)in)[i];
  half4v h;
  h[0] = (_Float16)v.x; h[1] = (_Float16)v.y; h[2] = (_Float16)v.z; h[3] = (_Float16)v.w;
  *(half4v*)(out + (size_t)i * 4) = h;
}

// ---- transpose + convert: W (1024x1024 f32, row-major [k][n]) -> Wt fp16 [n][k] ----
__global__ void transpose_f16_k(const float* __restrict__ W, _Float16* __restrict__ Wt) {
  __shared__ float tile[32][33];
  int tx = threadIdx.x, ty = threadIdx.y;
  int bx = blockIdx.x, by = blockIdx.y;
#pragma unroll
  for (int i = 0; i < 4; i++)
    tile[ty + i * 8][tx] = W[(size_t)(by * 32 + ty + i * 8) * 1024 + bx * 32 + tx];
  __syncthreads();
#pragma unroll
  for (int i = 0; i < 4; i++)
    Wt[(size_t)(bx * 32 + ty + i * 8) * 1024 + by * 32 + tx] = (_Float16)tile[tx][ty + i * 8];
}

// ---- GEMM: C[M x N] = fp16round(A[M x K] @ Bt[N x K]^T + bias) ; M=4096, K=1024 ----
// m97 structure: 128x128 tile, BK=32, 4 waves (2x2), global_load_lds width-16 staging.
template <int OUTF32>
__global__ __launch_bounds__(256, 2) void gemm_bt_k(
    const _Float16* __restrict__ A, const _Float16* __restrict__ Bt,
    const float* __restrict__ b0, const float* __restrict__ b1, const float* __restrict__ b2,
    void* __restrict__ Cv, int N) {
  __shared__ _Float16 As[128 * 32];
  __shared__ _Float16 Bs[128 * 32];
  const int K = 1024;
  int bx = blockIdx.x, by = blockIdx.y;
  int tid = threadIdx.x, lane = tid & 63, w = tid >> 6;
  int wr = w >> 1, wc = w & 1;
  int arow = lane & 15, ag = lane >> 4;
  int lr = lane >> 2, lc = lane & 3;  // staging: lane -> (row, 16B-chunk)

  f32x4 acc[4][4] = {};

  for (int kt = 0; kt < 32; ++kt) {
    int k0 = kt * 32;
#pragma unroll
    for (int i = 0; i < 2; i++) {
      gload16(A  + (size_t)(by * 128 + w * 32 + i * 16 + lr) * K + k0 + lc * 8,
              &As[(w * 32 + i * 16) * 32]);
      gload16(Bt + (size_t)(bx * 128 + w * 32 + i * 16 + lr) * K + k0 + lc * 8,
              &Bs[(w * 32 + i * 16) * 32]);
    }
    __syncthreads();  // drains vmcnt; tiles visible
    half8 a[4], b[4];
#pragma unroll
    for (int mi = 0; mi < 4; mi++)
      a[mi] = *(const half8*)&As[(wr * 64 + mi * 16 + arow) * 32 + ag * 8];
#pragma unroll
    for (int ni = 0; ni < 4; ni++)
      b[ni] = *(const half8*)&Bs[(wc * 64 + ni * 16 + arow) * 32 + ag * 8];
#pragma unroll
    for (int mi = 0; mi < 4; mi++)
#pragma unroll
      for (int ni = 0; ni < 4; ni++)
        acc[mi][ni] = __builtin_amdgcn_mfma_f32_16x16x32_f16(a[mi], b[ni], acc[mi][ni], 0, 0, 0);
    __syncthreads();  // protect LDS overwrite next iteration
  }

#pragma unroll
  for (int mi = 0; mi < 4; mi++) {
    int gr = by * 128 + wr * 64 + mi * 16 + ag * 4;
#pragma unroll
    for (int ni = 0; ni < 4; ni++) {
      int gc = bx * 128 + wc * 64 + ni * 16 + arow;
      const float* bp = gc < 1024 ? b0 : (gc < 2048 ? b1 : b2);
      float bb = bp[gc & 1023];
#pragma unroll
      for (int r = 0; r < 4; r++) {
        float val = acc[mi][ni][r] + bb;
        _Float16 hv = (_Float16)val;  // match reference fp16 rounding of matmul output
        if (OUTF32)
          ((float*)Cv)[(size_t)(gr + r) * N + gc] = (float)hv;
        else
          ((_Float16*)Cv)[(size_t)(gr + r) * N + gc] = hv;
      }
    }
  }
}

// ---- RoPE in-place on q,k parts of qkv (4096 x 3072 fp16). Folds scale^2=1/64 into q. ----
__global__ void rope_k(_Float16* __restrict__ qkv, const float* __restrict__ sin_t,
                       const float* __restrict__ cos_t) {
  int idx = blockIdx.x * 256 + threadIdx.x;  // 2^22 total
  int j = idx & 31;
  int h = (idx >> 5) & 15;
  int r = (idx >> 9) & 4095;
  int isK = idx >> 21;
  int pos = r & 511;
  _Float16* p = qkv + (size_t)r * 3072 + isK * 1024 + h * 64 + j;
  float a = (float)p[0], b = (float)p[32];
  float sn = sin_t[pos * 32 + j], cs = cos_t[pos * 32 + j];
  float o0 = a * cs - b * sn;
  float o1 = b * cs + a * sn;
  if (!isK) { o0 *= 0.015625f; o1 *= 0.015625f; }  // scale^2 = HD^-1 = 1/64
  p[0] = (_Float16)o0;
  p[32] = (_Float16)o1;
}

// ---- Fused attention: one block per (q-tile 64, head, batch); 4 waves x 16 q-rows ----
__global__ __launch_bounds__(256, 2) void attn_k(const _Float16* __restrict__ qkv,
                                                 _Float16* __restrict__ out) {
  int qt = blockIdx.x, h = blockIdx.y, b = blockIdx.z;
  int tid = threadIdx.x, lane = tid & 63, w = tid >> 6;
  int arow = lane & 15, ag = lane >> 4;

  __shared__ _Float16 Vt[64][72];       // V^T [hd][s], +8 pad (row = 144B, 16B aligned)
  __shared__ _Float16 Pl[4][16][72];    // per-wave P [qrow][s], +8 pad

  int qrow0 = b * 512 + qt * 64 + w * 16;
  const _Float16* Qp = qkv + (size_t)qrow0 * 3072 + h * 64;
  half8 qa[2];
#pragma unroll
  for (int ks = 0; ks < 2; ks++)
    qa[ks] = *(const half8*)(Qp + (size_t)arow * 3072 + ks * 32 + ag * 8);

  const _Float16* Kb = qkv + (size_t)(b * 512) * 3072 + 1024 + h * 64;
  const _Float16* Vb = qkv + (size_t)(b * 512) * 3072 + 2048 + h * 64;

  float m[4], ls[4];
  f32x4 oacc[4] = {};
#pragma unroll
  for (int r = 0; r < 4; r++) { m[r] = -__builtin_inff(); ls[r] = 0.f; }

  for (int st = 0; st < 8; ++st) {
    __syncthreads();  // previous PV reads done before Vt overwrite
    {  // stage V^T: 256 threads x 16 elements
      int vr = tid >> 2, c0 = (tid & 3) * 16;
      const _Float16* vp = Vb + (size_t)(st * 64 + vr) * 3072 + c0;
      half8 v0 = *(const half8*)vp;
      half8 v1 = *(const half8*)(vp + 8);
#pragma unroll
      for (int j = 0; j < 8; j++) Vt[c0 + j][vr] = v0[j];
#pragma unroll
      for (int j = 0; j < 8; j++) Vt[c0 + 8 + j][vr] = v1[j];
    }
    // logits: Q (A) x K (B), 4 col-chunks of 16 s-positions
    f32x4 lg[4];
#pragma unroll
    for (int c = 0; c < 4; c++) {
      f32x4 a0 = {};
#pragma unroll
      for (int ks = 0; ks < 2; ks++) {
        half8 kb = *(const half8*)(Kb + (size_t)(st * 64 + c * 16 + arow) * 3072 + ks * 32 + ag * 8);
        a0 = __builtin_amdgcn_mfma_f32_16x16x32_f16(qa[ks], kb, a0, 0, 0, 0);
      }
      lg[c] = a0;
    }
    // online softmax (rows owned: ag*4 + r; reduce across 16 lanes of same ag-group)
    float alpha[4];
    _Float16 ph[4][4];
#pragma unroll
    for (int r = 0; r < 4; r++) {
      float tm = fmaxf(fmaxf(lg[0][r], lg[1][r]), fmaxf(lg[2][r], lg[3][r]));
#pragma unroll
      for (int d = 1; d < 16; d <<= 1) tm = fmaxf(tm, __shfl_xor(tm, d, 16));
      float mn = fmaxf(m[r], tm);
      alpha[r] = expf(m[r] - mn);
      m[r] = mn;
      float ps = 0.f;
#pragma unroll
      for (int c = 0; c < 4; c++) {
        float p = expf(lg[c][r] - mn);
        ps += p;
        ph[c][r] = (_Float16)p;
      }
#pragma unroll
      for (int d = 1; d < 16; d <<= 1) ps += __shfl_xor(ps, d, 16);
      ls[r] = ls[r] * alpha[r] + ps;
#pragma unroll
      for (int c = 0; c < 4; c++) oacc[c][r] *= alpha[r];
    }
    // P -> LDS (per-wave private region)
#pragma unroll
    for (int c = 0; c < 4; c++)
#pragma unroll
      for (int r = 0; r < 4; r++) Pl[w][ag * 4 + r][c * 16 + arow] = ph[c][r];
    __syncthreads();  // Vt + P visible
    // PV: out[16x64] += P[16x64] @ V[64x64]
#pragma unroll
    for (int ks = 0; ks < 2; ks++) {
      half8 pa = *(const half8*)&Pl[w][arow][ks * 32 + ag * 8];
#pragma unroll
      for (int c = 0; c < 4; c++) {
        half8 vb = *(const half8*)&Vt[c * 16 + arow][ks * 32 + ag * 8];
        oacc[c] = __builtin_amdgcn_mfma_f32_16x16x32_f16(pa, vb, oacc[c], 0, 0, 0);
      }
    }
  }
  // epilogue: normalize, fp16 round (reference casts attn out to fp16), store
#pragma unroll
  for (int c = 0; c < 4; c++)
#pragma unroll
    for (int r = 0; r < 4; r++) {
      float v = oacc[c][r] / ls[r];
      out[(size_t)(qrow0 + ag * 4 + r) * 1024 + h * 64 + c * 16 + arow] = (_Float16)v;
    }
}

extern "C" void kernel_launch(void* const* d_in, const int* in_sizes, int n_in,
                              void* d_out, int out_size, void* d_ws, size_t ws_size,
                              hipStream_t stream) {
  const float* x  = (const float*)d_in[0];
  const float* Wq = (const float*)d_in[1];
  const float* bq = (const float*)d_in[2];
  const float* Wk = (const float*)d_in[3];
  const float* bk = (const float*)d_in[4];
  const float* Wv = (const float*)d_in[5];
  const float* bv = (const float*)d_in[6];
  const float* Wo = (const float*)d_in[7];
  const float* bo = (const float*)d_in[8];

  char* ws = (char*)d_ws;
  float* sin_t    = (float*)(ws + OFF_SIN);
  float* cos_t    = (float*)(ws + OFF_COS);
  _Float16* xh    = (_Float16*)(ws + OFF_XH);
  _Float16* wqkvt = (_Float16*)(ws + OFF_WQKVT);
  _Float16* wot   = (_Float16*)(ws + OFF_WOT);
  _Float16* qkv   = (_Float16*)(ws + OFF_QKV);
  _Float16* attn  = (_Float16*)(ws + OFF_ATTN);

  rope_table_k<<<64, 256, 0, stream>>>(sin_t, cos_t);
  convert_f16_k<<<4096, 256, 0, stream>>>(x, xh, 1048576);
  dim3 tb(32, 8), tg(32, 32);
  transpose_f16_k<<<tg, tb, 0, stream>>>(Wq, wqkvt);
  transpose_f16_k<<<tg, tb, 0, stream>>>(Wk, wqkvt + 1024 * 1024);
  transpose_f16_k<<<tg, tb, 0, stream>>>(Wv, wqkvt + 2 * 1024 * 1024);
  transpose_f16_k<<<tg, tb, 0, stream>>>(Wo, wot);
  // qkv = fp16(x @ [Wq|Wk|Wv] + b)
  gemm_bt_k<0><<<dim3(24, 32), 256, 0, stream>>>(xh, wqkvt, bq, bk, bv, qkv, 3072);
  // rope on q,k (q also gets scale^2)
  rope_k<<<16384, 256, 0, stream>>>(qkv, sin_t, cos_t);
  // attention
  attn_k<<<dim3(8, 16, 8), 256, 0, stream>>>(qkv, attn);
  // out = fp16(attn @ Wo + bo) stored as f32
  gemm_bt_k<1><<<dim3(8, 32), 256, 0, stream>>>(attn, wot, bo, bo, bo, d_out, 1024);
}